// Round 16
// baseline (61.752 us; speedup 1.0000x reference)
//
#include <hip/hip_runtime.h>
#include <hip/hip_bf16.h>
#include <hip/hip_fp16.h>

// HeadUpdator: fused bilinear-upsample+sigmoid+einsum (MFMA) + per-row gating MLP.
// feat (8,64,256,256) f32, head (8,80,64,1) f32, pred (8,80,128,128) f32
// -> out (8,80,64,1,1) f32.
// Round-16: feat staged via global_load_lds (DMA queue holds in-flight state,
// not VGPRs -- the allocator provably won't carry deep register batches).
// Pred loads issue first (fenced) so their waits never drain the stage queue.
// Feat LDS uses the Pfrag-proven 16B-slot bijection per 1KB sub-fragment,
// staged with pre-permuted per-lane global source (linear LDS dest, G21).

using bf16x8 = __attribute__((ext_vector_type(8))) short;
using f32x4  = __attribute__((ext_vector_type(4))) float;

#define SCHED_FENCE() __builtin_amdgcn_sched_barrier(0)
#define LGKM_BARRIER() do { \
  asm volatile("s_waitcnt lgkmcnt(0)" ::: "memory"); \
  __builtin_amdgcn_s_barrier(); } while (0)

__device__ __forceinline__ unsigned pk2(float lo, float hi) {
  union { __hip_bfloat162 h2; unsigned u; } cv;
  cv.h2 = __float22bfloat162_rn(make_float2(lo, hi));
  return cv.u;
}
// sigmoid(0.25a + 0.75b), -log2e folded into the lerp weights
__device__ __forceinline__ float sigAB(float a, float b) {
  return __builtin_amdgcn_rcpf(1.0f + __builtin_amdgcn_exp2f(-0.36067376f * a - 1.08202128f * b));
}
// sigmoid(0.75a + 0.25b)
__device__ __forceinline__ float sigBA(float a, float b) {
  return __builtin_amdgcn_rcpf(1.0f + __builtin_amdgcn_exp2f(-1.08202128f * a - 0.36067376f * b));
}

// ---------------- Kernel 1a: half-row assemble (big ws) ----------------
// grid = 4096 (8 b x 256 h x 2 half), 256 threads, LDS 52 KB (3 blocks/CU).
// Feat LDS: per wave 8 KB = [ks 0..3][h2 0..1][64 slots x 16B]; slot for lane
// (ch16,kg) = kg*16 + ((ch16 ^ ks ^ (kg<<1))&15)  (r8-family bijection,
// measured 0 conflicts). Stage inst i (=ks*2+h2) writes LDS linearly
// (base + lane*16); lane l decodes (kg_r=l>>4, y=l&15) -> ch_r =
// (y ^ ks ^ (kg_r<<1))&15, src px = ks*32 + kg_r*8 + h2*4.
__global__ __launch_bounds__(256) void k_assemble_half(
    const float* __restrict__ feat, const float* __restrict__ pred,
    __half* __restrict__ partial) {
  __shared__ __align__(16) float FeatLds[4][2048];             // 32 KB (8 KB/wave)
  __shared__ __align__(16) unsigned short Pfrag[20 * 64 * 8];  // 20 KB

  // XCD-chunked bijective swizzle (nwg=4096): XCD x owns batch b=x.
  const int bid = blockIdx.x;
  const int wg  = (bid & 7) * 512 + (bid >> 3);
  const int half = wg & 1;
  const int h    = (wg >> 1) & 255;
  const int b    = wg >> 9;

  const int tid = threadIdx.x;
  const int gg = tid & 15, nbp = tid >> 4;           // pred-phase coords
  const int wid = tid >> 6, l = tid & 63;            // mfma-phase coords
  const int ch16 = l & 15, kg = l >> 4, c0 = wid << 4;

  const int j = h >> 1;
  int r0, r1; float wy0, wy1;
  if ((h & 1) == 0) { r0 = (j > 0) ? j - 1 : 0; r1 = j; wy0 = 0.25f; wy1 = 0.75f; }
  else              { r0 = j; r1 = (j < 127) ? j + 1 : 127; wy0 = 0.75f; wy1 = 0.25f; }

  const int cbase = half << 6;          // 0 or 64 (16B aligned)
  const int csc   = 64 - half;          // halo col: 64 (half0) / 63 (half1)
  const float* pbat = pred + (((size_t)(b * 80)) << 14);

  // ---- Region A: pred loads FIRST in the vmcnt queue (regs; consumed soon).
  f32x4 p0[5], p1[5];
  float s0[5], s1[5];
  #pragma unroll
  for (int i = 0; i < 5; ++i) {
    const float* pb = pbat + (((size_t)(nbp + 16 * i)) << 14);
    p0[i] = *(const f32x4*)(pb + (r0 << 7) + cbase + 4 * gg);
    p1[i] = *(const f32x4*)(pb + (r1 << 7) + cbase + 4 * gg);
    s0[i] = pb[(r0 << 7) + csc];
    s1[i] = pb[(r1 << 7) + csc];
  }
  SCHED_FENCE();

  // ---- Region B: 8 global_load_lds stages per wave (8 KB in flight, no regs).
  {
    const float* fbase = feat + (((size_t)(b * 64 + c0)) << 16) + h * 256 + (half << 7);
    const int kg_r = l >> 4, y = l & 15;
    #pragma unroll
    for (int i = 0; i < 8; ++i) {
      const int ks = i >> 1, h2 = i & 1;
      const int ch_r = (y ^ ks ^ (kg_r << 1)) & 15;
      const float* src = fbase + (((size_t)ch_r) << 16) + ks * 32 + kg_r * 8 + h2 * 4;
      __builtin_amdgcn_global_load_lds(
          (const __attribute__((address_space(1))) void*)src,
          (__attribute__((address_space(3))) void*)((char*)&FeatLds[wid][0] + i * 1024),
          16, 0, 0);
    }
  }
  SCHED_FENCE();

  // ---- Region C: v-lerp + h-lerp + sigmoid -> Pfrag (stage queue rides).
  #pragma unroll
  for (int i = 0; i < 5; ++i) {
    const float sc = wy0 * s0[i] + wy1 * s1[i];
    const float y0 = wy0 * p0[i][0] + wy1 * p1[i][0];
    const float y1 = wy0 * p0[i][1] + wy1 * p1[i][1];
    const float y2 = wy0 * p0[i][2] + wy1 * p1[i][2];
    const float y3 = wy0 * p0[i][3] + wy1 * p1[i][3];
    float yl = __shfl_up(y3, 1, 16);
    float yr = __shfl_down(y0, 1, 16);
    if (gg == 0)  yl = half ? sc : y0;   // left edge: scalar col 63 / clamp
    if (gg == 15) yr = half ? y3 : sc;   // right edge: clamp / scalar col 64
    float P[8];
    P[0] = sigAB(yl, y0); P[1] = sigBA(y0, y1);
    P[2] = sigAB(y0, y1); P[3] = sigBA(y1, y2);
    P[4] = sigAB(y1, y2); P[5] = sigBA(y2, y3);
    P[6] = sigAB(y2, y3); P[7] = sigBA(y3, yr);
    uint4 s;
    s.x = pk2(P[0], P[1]); s.y = pk2(P[2], P[3]);
    s.z = pk2(P[4], P[5]); s.w = pk2(P[6], P[7]);
    const int ks = gg >> 2, kgw = gg & 3;
    const int slot = kgw * 16 + ((nbp ^ ks ^ (kgw << 1)) & 15);
    *(uint4*)&Pfrag[(((ks * 5 + i) * 64) + slot) * 8] = s;
  }
  __syncthreads();   // drains vmcnt(0)+lgkmcnt(0): feat staged, Pfrag ready.

  // ---- MFMA: both operands from LDS (proven conflict-free slot pattern).
  f32x4 acc[5] = {};
  const char* fw = (const char*)&FeatLds[wid][0];
  #pragma unroll
  for (int ks = 0; ks < 4; ++ks) {
    const int slot = kg * 16 + ((ch16 ^ ks ^ (kg << 1)) & 15);
    const f32x4 f0 = *(const f32x4*)(fw + ks * 2048 + slot * 16);
    const f32x4 f1 = *(const f32x4*)(fw + ks * 2048 + 1024 + slot * 16);
    union { uint4 u; bf16x8 v; } bu;
    bu.u.x = pk2(f0[0], f0[1]); bu.u.y = pk2(f0[2], f0[3]);
    bu.u.z = pk2(f1[0], f1[1]); bu.u.w = pk2(f1[2], f1[3]);
    #pragma unroll
    for (int m = 0; m < 5; ++m) {
      const bf16x8 af = *(const bf16x8*)&Pfrag[(((ks * 5 + m) * 64) + slot) * 8];
      acc[m] = __builtin_amdgcn_mfma_f32_16x16x32_bf16(af, bu.v, acc[m], 0, 0, 0);
    }
  }

  // D frag: col = lane&15 (channel), row = (lane>>4)*4 + q (class).
  __half* po = partial + ((size_t)(b * 512 + h * 2 + half)) * (80 * 64);
  #pragma unroll
  for (int m = 0; m < 5; ++m) {
    #pragma unroll
    for (int q = 0; q < 4; ++q) {
      const int n = m * 16 + kg * 4 + q;
      po[n * 64 + c0 + ch16] = __float2half(acc[m][q]);
    }
  }
}

// ---------------- Kernel 1b: round-8 fallback (ws < 42 MB) ----------------
__global__ __launch_bounds__(256) void k_assemble_full(
    const float* __restrict__ feat, const float* __restrict__ pred,
    __half* __restrict__ partial) {
  __shared__ __align__(16) unsigned short Pfrag[40 * 64 * 8];  // 40 KB

  const int tid = threadIdx.x;
  const int b  = blockIdx.x >> 7;
  const int rb = blockIdx.x & 127;
  const int wid = tid >> 6, l = tid & 63;
  const int ch16 = l & 15, kg = l >> 4;
  const int c0 = wid << 4;
  const int h0 = rb * 2;
  const int gg = tid & 31, nb = tid >> 5;

  f32x4 acc[5] = {};
  const float* fwave = feat + (((size_t)(b * 64 + c0 + ch16)) << 16);
  const float* pbat  = pred + (((size_t)(b * 80)) << 14);

  #pragma unroll
  for (int r = 0; r < 2; ++r) {
    const int h = h0 + r;
    const int j = h >> 1;
    int r0, r1; float wy0, wy1;
    if ((h & 1) == 0) { r0 = (j > 0) ? j - 1 : 0; r1 = j; wy0 = 0.25f; wy1 = 0.75f; }
    else              { r0 = j; r1 = (j < 127) ? j + 1 : 127; wy0 = 0.75f; wy1 = 0.25f; }

    float4 p0[10], p1[10];
    #pragma unroll
    for (int i = 0; i < 10; ++i) {
      const float* pb = pbat + (((size_t)(nb + 8 * i)) << 14);
      p0[i] = *(const float4*)(pb + (r0 << 7) + gg * 4);
      p1[i] = *(const float4*)(pb + (r1 << 7) + gg * 4);
    }
    SCHED_FENCE();

    const float* fb = fwave + h * 256;
    float4 f[16];
    #pragma unroll
    for (int ks = 0; ks < 8; ++ks) {
      const int pw = ks * 32 + kg * 8;
      f[2 * ks]     = *(const float4*)(fb + pw);
      f[2 * ks + 1] = *(const float4*)(fb + pw + 4);
    }
    SCHED_FENCE();

    #pragma unroll
    for (int i = 0; i < 10; ++i) {
      const int n = nb + 8 * i;
      const float y0 = wy0 * p0[i].x + wy1 * p1[i].x;
      const float y1 = wy0 * p0[i].y + wy1 * p1[i].y;
      const float y2 = wy0 * p0[i].z + wy1 * p1[i].z;
      const float y3 = wy0 * p0[i].w + wy1 * p1[i].w;
      float yl = __shfl_up(y3, 1, 64);   if (gg == 0)  yl = y0;
      float yr = __shfl_down(y0, 1, 64); if (gg == 31) yr = y3;
      float P[8];
      P[0] = sigAB(yl, y0); P[1] = sigBA(y0, y1);
      P[2] = sigAB(y0, y1); P[3] = sigBA(y1, y2);
      P[4] = sigAB(y1, y2); P[5] = sigBA(y2, y3);
      P[6] = sigAB(y2, y3); P[7] = sigBA(y3, yr);
      uint4 s;
      s.x = pk2(P[0], P[1]); s.y = pk2(P[2], P[3]);
      s.z = pk2(P[4], P[5]); s.w = pk2(P[6], P[7]);
      const int ks = gg >> 2, kgw = gg & 3;
      const int slot = kgw * 16 + (((n & 15) ^ ks ^ (kgw << 1)) & 15);
      *(uint4*)&Pfrag[(((ks * 5 + (n >> 4)) * 64) + slot) * 8] = s;
    }
    LGKM_BARRIER();

    #pragma unroll
    for (int ks = 0; ks < 8; ++ks) {
      const float4 f0 = f[2 * ks], f1 = f[2 * ks + 1];
      union { uint4 u; bf16x8 v; } bu;
      bu.u.x = pk2(f0.x, f0.y); bu.u.y = pk2(f0.z, f0.w);
      bu.u.z = pk2(f1.x, f1.y); bu.u.w = pk2(f1.z, f1.w);
      const int slot = kg * 16 + ((ch16 ^ ks ^ (kg << 1)) & 15);
      #pragma unroll
      for (int m = 0; m < 5; ++m) {
        const bf16x8 af = *(const bf16x8*)&Pfrag[(((ks * 5 + m) * 64) + slot) * 8];
        acc[m] = __builtin_amdgcn_mfma_f32_16x16x32_bf16(af, bu.v, acc[m], 0, 0, 0);
      }
    }
    LGKM_BARRIER();
  }

  __half* po = partial + ((size_t)(b * 128 + rb)) * (80 * 64);
  #pragma unroll
  for (int m = 0; m < 5; ++m) {
    #pragma unroll
    for (int q = 0; q < 4; ++q) {
      const int n = m * 16 + kg * 4 + q;
      po[n * 64 + c0 + ch16] = __float2half(acc[m][q]);
    }
  }
}

// ---------------- Kernel 2: reduce + head-update chain ----------------
__device__ __forceinline__ float wred64(float v) {
  #pragma unroll
  for (int off = 32; off > 0; off >>= 1) v += __shfl_xor(v, off, 64);
  return v;
}
__device__ __forceinline__ float lnorm(float x, const float* __restrict__ g,
                                       const float* __restrict__ be, int l) {
  const float m = wred64(x) * 0.015625f;
  const float d = x - m;
  const float var = wred64(d * d) * 0.015625f;
  return d * rsqrtf(var + 1e-5f) * g[l] + be[l];
}
__device__ __forceinline__ float sigmf(float x) {
  return __builtin_amdgcn_rcpf(1.0f + __builtin_amdgcn_exp2f(-1.44269504f * x));
}

// grid = 640 blocks (one per output row), 256 threads.
__global__ __launch_bounds__(256) void k_head(
    const __half* __restrict__ partial, const float* __restrict__ head,
    const float* __restrict__ Wpt, const float* __restrict__ bpt,
    const float* __restrict__ Wht, const float* __restrict__ bht,
    const float* __restrict__ Wpg, const float* __restrict__ bpg,
    const float* __restrict__ Whg, const float* __restrict__ bhg,
    const float* __restrict__ Wfc, const float* __restrict__ bfc,
    const float* __restrict__ g_pin, const float* __restrict__ be_pin,
    const float* __restrict__ g_hin, const float* __restrict__ be_hin,
    const float* __restrict__ g_pout, const float* __restrict__ be_pout,
    const float* __restrict__ g_hout, const float* __restrict__ be_hout,
    const float* __restrict__ g_fc, const float* __restrict__ be_fc,
    float* __restrict__ out, int npart) {
  __shared__ float red[4][64];
  __shared__ float buf[4][64];   // a, hd, gate, upd
  const int tid = threadIdx.x, c = tid & 63, q = tid >> 6;
  const int r = blockIdx.x;              // [0,640)
  const int b = r / 80, n = r % 80;
  const int npq = npart >> 2;

  const __half* pp = partial + ((size_t)b * npart + (size_t)q * npq) * 5120 + n * 64 + c;
  float s = 0.f;
  #pragma unroll 8
  for (int jj = 0; jj < npq; ++jj) s += __half2float(pp[(size_t)jj * 5120]);
  red[q][c] = s;
  __syncthreads();

  if (q == 0) {
    const float a_c = red[0][c] + red[1][c] + red[2][c] + red[3][c];
    buf[0][c] = a_c;
    buf[1][c] = head[(size_t)r * 64 + c];

    float pf_in = bpt[c], pf_out = bpt[64 + c];
    float hf_in = bht[c], hf_out = bht[64 + c];
    #pragma unroll 8
    for (int k = 0; k < 64; ++k) {
      const float av = buf[0][k];
      const float hv = buf[1][k];
      pf_in  += av * Wpt[k * 128 + c];
      pf_out += av * Wpt[k * 128 + 64 + c];
      hf_in  += hv * Wht[k * 128 + c];
      hf_out += hv * Wht[k * 128 + 64 + c];
    }
    buf[2][c] = hf_in * pf_in;

    float hg = bhg[c], pg = bpg[c];
    #pragma unroll 8
    for (int k = 0; k < 64; ++k) {
      const float gv = buf[2][k];
      hg += gv * Whg[k * 64 + c];
      pg += gv * Wpg[k * 64 + c];
    }
    const float head_gate = sigmf(lnorm(hg, g_hin, be_hin, c));
    const float pred_gate = sigmf(lnorm(pg, g_pin, be_pin, c));
    const float hfo = lnorm(hf_out, g_hout, be_hout, c);
    const float pfo = lnorm(pf_out, g_pout, be_pout, c);
    buf[3][c] = pred_gate * pfo + head_gate * hfo;

    float fc = bfc[c];
    #pragma unroll 8
    for (int k = 0; k < 64; ++k)
      fc += buf[3][k] * Wfc[k * 64 + c];
    float o = lnorm(fc, g_fc, be_fc, c);
    out[(size_t)r * 64 + c] = fmaxf(o, 0.f);
  }
}

extern "C" void kernel_launch(void* const* d_in, const int* in_sizes, int n_in,
                              void* d_out, int out_size, void* d_ws, size_t ws_size,
                              hipStream_t stream) {
  const float* feat   = (const float*)d_in[0];
  const float* head   = (const float*)d_in[1];
  const float* pred   = (const float*)d_in[2];
  const float* Wpt    = (const float*)d_in[3];
  const float* bpt    = (const float*)d_in[4];
  const float* Wht    = (const float*)d_in[5];
  const float* bht    = (const float*)d_in[6];
  const float* Wpg    = (const float*)d_in[7];
  const float* bpg    = (const float*)d_in[8];
  const float* Whg    = (const float*)d_in[9];
  const float* bhg    = (const float*)d_in[10];
  const float* Wfc    = (const float*)d_in[11];
  const float* bfc    = (const float*)d_in[12];
  const float* g_pin  = (const float*)d_in[13];
  const float* be_pin = (const float*)d_in[14];
  const float* g_hin  = (const float*)d_in[15];
  const float* be_hin = (const float*)d_in[16];
  const float* g_pout = (const float*)d_in[17];
  const float* be_pout= (const float*)d_in[18];
  const float* g_hout = (const float*)d_in[19];
  const float* be_hout= (const float*)d_in[20];
  const float* g_fc   = (const float*)d_in[21];
  const float* be_fc  = (const float*)d_in[22];
  float* out = (float*)d_out;
  __half* partial = (__half*)d_ws;

  const bool big = ws_size >= (size_t)8 * 512 * 5120 * 2;  // 41.94 MB (proven)
  const int npart = big ? 512 : 128;

  if (big)
    hipLaunchKernelGGL(k_assemble_half, dim3(4096), dim3(256), 0, stream,
                       feat, pred, partial);
  else
    hipLaunchKernelGGL(k_assemble_full, dim3(1024), dim3(256), 0, stream,
                       feat, pred, partial);

  hipLaunchKernelGGL(k_head, dim3(640), dim3(256), 0, stream,
                     partial, head, Wpt, bpt, Wht, bht, Wpg, bpg, Whg, bhg,
                     Wfc, bfc, g_pin, be_pin, g_hin, be_hin, g_pout, be_pout,
                     g_hout, be_hout, g_fc, be_fc, out, npart);
}

// Round 17
// 55.129 us; speedup vs baseline: 1.1201x; 1.1201x over previous
//
#include <hip/hip_runtime.h>
#include <hip/hip_bf16.h>
#include <hip/hip_fp16.h>

// HeadUpdator: fused bilinear-upsample+sigmoid+einsum (MFMA) + per-row gating MLP.
// feat (8,64,256,256) f32, head (8,80,64,1) f32, pred (8,80,128,128) f32
// -> out (8,80,64,1,1) f32.
// Round-17: BYTE ECONOMY. r16 falsified queue-depth (96KB/CU in flight, BW
// unchanged); multiple structures converge at ~60us = ~426MB moved / ~7TB/s
// aggregate service. So cut bytes: pair output rows (2jp,2jp+1) per block --
// they share pred row jp (3 rowsets not 4) and sum into ONE acc -> ONE
// partial slot (npart 256, partial traffic halved). Body = r13's proven shape.

using bf16x8 = __attribute__((ext_vector_type(8))) short;
using f32x4  = __attribute__((ext_vector_type(4))) float;

#define SCHED_FENCE() __builtin_amdgcn_sched_barrier(0)
#define LGKM_BARRIER() do { \
  asm volatile("s_waitcnt lgkmcnt(0)" ::: "memory"); \
  __builtin_amdgcn_s_barrier(); } while (0)

__device__ __forceinline__ unsigned pk2(float lo, float hi) {
  union { __hip_bfloat162 h2; unsigned u; } cv;
  cv.h2 = __float22bfloat162_rn(make_float2(lo, hi));
  return cv.u;
}
// sigmoid(0.25a + 0.75b), -log2e folded into the lerp weights
__device__ __forceinline__ float sigAB(float a, float b) {
  return __builtin_amdgcn_rcpf(1.0f + __builtin_amdgcn_exp2f(-0.36067376f * a - 1.08202128f * b));
}
// sigmoid(0.75a + 0.25b)
__device__ __forceinline__ float sigBA(float a, float b) {
  return __builtin_amdgcn_rcpf(1.0f + __builtin_amdgcn_exp2f(-1.08202128f * a - 0.36067376f * b));
}

// ---------------- Kernel 1a: row-pair half assemble (big ws) ----------------
// grid = 2048 (8 b x 128 jp x 2 half), 256 threads, LDS 20 KB (8 blocks/CU).
// Block covers output rows 2jp (pred rows jp-1,jp; w .25/.75) and 2jp+1
// (pred rows jp,jp+1; w .75/.25). p1 = row jp persists; p0/s0 reload as
// row jp+1 for the odd row. Both rows' pixel sums accumulate into one acc.
// Pred/Pfrag thread maps and slot bijection = r13 (measured 0 conflicts).
__global__ __launch_bounds__(256, 4) void k_assemble_pair(
    const float* __restrict__ feat, const float* __restrict__ pred,
    __half* __restrict__ partial) {
  __shared__ __align__(16) unsigned short Pfrag[20 * 64 * 8];  // 20 KB

  // XCD-chunked bijective swizzle (nwg=2048, 256 per XCD).
  const int bid = blockIdx.x;
  const int wg  = (bid & 7) * 256 + (bid >> 3);
  const int half = wg & 1;
  const int jp   = (wg >> 1) & 127;
  const int b    = wg >> 8;

  const int tid = threadIdx.x;
  const int gg = tid & 15, nbp = tid >> 4;           // pred-phase coords
  const int wid = tid >> 6, l = tid & 63;            // mfma-phase coords
  const int ch16 = l & 15, kg = l >> 4, c0 = wid << 4;

  const int rA = (jp > 0) ? jp - 1 : 0;      // even row's low pred row
  const int rB = jp;                          // shared pred row
  const int rC = (jp < 127) ? jp + 1 : 127;   // odd row's high pred row

  const int cbase = half << 6;          // 0 or 64 (16B aligned)
  const int csc   = 64 - half;          // halo col: 64 (half0) / 63 (half1)
  const float* pbat = pred + (((size_t)(b * 80)) << 14);
  const float* fbase = feat + (((size_t)(b * 64 + c0 + ch16)) << 16) + (half << 7);

  f32x4 acc[5] = {};
  float4 p0[5], p1[5];
  float s0[5], s1[5];

  // ==== ROW EVEN (h = 2jp): p0=rowA(.25), p1=rowB(.75) ====
  #pragma unroll
  for (int i = 0; i < 5; ++i) {
    const float* pb = pbat + (((size_t)(nbp + 16 * i)) << 14);
    p0[i] = *(const float4*)(pb + (rA << 7) + cbase + 4 * gg);
    p1[i] = *(const float4*)(pb + (rB << 7) + cbase + 4 * gg);
    s0[i] = pb[(rA << 7) + csc];
    s1[i] = pb[(rB << 7) + csc];
  }
  #pragma unroll
  for (int i = 0; i < 5; ++i) {
    const float sc = 0.25f * s0[i] + 0.75f * s1[i];
    const float y0 = 0.25f * p0[i].x + 0.75f * p1[i].x;
    const float y1 = 0.25f * p0[i].y + 0.75f * p1[i].y;
    const float y2 = 0.25f * p0[i].z + 0.75f * p1[i].z;
    const float y3 = 0.25f * p0[i].w + 0.75f * p1[i].w;
    float yl = __shfl_up(y3, 1, 16);
    float yr = __shfl_down(y0, 1, 16);
    if (gg == 0)  yl = half ? sc : y0;
    if (gg == 15) yr = half ? y3 : sc;
    float P[8];
    P[0] = sigAB(yl, y0); P[1] = sigBA(y0, y1);
    P[2] = sigAB(y0, y1); P[3] = sigBA(y1, y2);
    P[4] = sigAB(y1, y2); P[5] = sigBA(y2, y3);
    P[6] = sigAB(y2, y3); P[7] = sigBA(y3, yr);
    uint4 s;
    s.x = pk2(P[0], P[1]); s.y = pk2(P[2], P[3]);
    s.z = pk2(P[4], P[5]); s.w = pk2(P[6], P[7]);
    const int ks = gg >> 2, kgw = gg & 3;
    const int slot = kgw * 16 + ((nbp ^ ks ^ (kgw << 1)) & 15);
    *(uint4*)&Pfrag[(((ks * 5 + i) * 64) + slot) * 8] = s;
  }
  __syncthreads();

  // Reload p0/s0 as row rC for the odd row (in flight during MFMA-even).
  #pragma unroll
  for (int i = 0; i < 5; ++i) {
    const float* pb = pbat + (((size_t)(nbp + 16 * i)) << 14);
    p0[i] = *(const float4*)(pb + (rC << 7) + cbase + 4 * gg);
    s0[i] = pb[(rC << 7) + csc];
  }

  // MFMA row even: feat loads inline (r13's measured-best shape).
  {
    const float* fb = fbase + (2 * jp) * 256;
    #pragma unroll
    for (int ks = 0; ks < 4; ++ks) {
      const int pw = ks * 32 + kg * 8;
      const float4 f0 = *(const float4*)(fb + pw);
      const float4 f1 = *(const float4*)(fb + pw + 4);
      union { uint4 u; bf16x8 v; } bu;
      bu.u.x = pk2(f0.x, f0.y); bu.u.y = pk2(f0.z, f0.w);
      bu.u.z = pk2(f1.x, f1.y); bu.u.w = pk2(f1.z, f1.w);
      const int slot = kg * 16 + ((ch16 ^ ks ^ (kg << 1)) & 15);
      #pragma unroll
      for (int m = 0; m < 5; ++m) {
        const bf16x8 af = *(const bf16x8*)&Pfrag[(((ks * 5 + m) * 64) + slot) * 8];
        acc[m] = __builtin_amdgcn_mfma_f32_16x16x32_bf16(af, bu.v, acc[m], 0, 0, 0);
      }
    }
  }
  __syncthreads();   // all waves done reading Pfrag before overwrite

  // ==== ROW ODD (h = 2jp+1): p1=rowB(.75), p0=rowC(.25) -- same weights ====
  #pragma unroll
  for (int i = 0; i < 5; ++i) {
    const float sc = 0.25f * s0[i] + 0.75f * s1[i];
    const float y0 = 0.25f * p0[i].x + 0.75f * p1[i].x;
    const float y1 = 0.25f * p0[i].y + 0.75f * p1[i].y;
    const float y2 = 0.25f * p0[i].z + 0.75f * p1[i].z;
    const float y3 = 0.25f * p0[i].w + 0.75f * p1[i].w;
    float yl = __shfl_up(y3, 1, 16);
    float yr = __shfl_down(y0, 1, 16);
    if (gg == 0)  yl = half ? sc : y0;
    if (gg == 15) yr = half ? y3 : sc;
    float P[8];
    P[0] = sigAB(yl, y0); P[1] = sigBA(y0, y1);
    P[2] = sigAB(y0, y1); P[3] = sigBA(y1, y2);
    P[4] = sigAB(y1, y2); P[5] = sigBA(y2, y3);
    P[6] = sigAB(y2, y3); P[7] = sigBA(y3, yr);
    uint4 s;
    s.x = pk2(P[0], P[1]); s.y = pk2(P[2], P[3]);
    s.z = pk2(P[4], P[5]); s.w = pk2(P[6], P[7]);
    const int ks = gg >> 2, kgw = gg & 3;
    const int slot = kgw * 16 + ((nbp ^ ks ^ (kgw << 1)) & 15);
    *(uint4*)&Pfrag[(((ks * 5 + i) * 64) + slot) * 8] = s;
  }
  __syncthreads();

  // MFMA row odd accumulates into the SAME acc.
  {
    const float* fb = fbase + (2 * jp + 1) * 256;
    #pragma unroll
    for (int ks = 0; ks < 4; ++ks) {
      const int pw = ks * 32 + kg * 8;
      const float4 f0 = *(const float4*)(fb + pw);
      const float4 f1 = *(const float4*)(fb + pw + 4);
      union { uint4 u; bf16x8 v; } bu;
      bu.u.x = pk2(f0.x, f0.y); bu.u.y = pk2(f0.z, f0.w);
      bu.u.z = pk2(f1.x, f1.y); bu.u.w = pk2(f1.z, f1.w);
      const int slot = kg * 16 + ((ch16 ^ ks ^ (kg << 1)) & 15);
      #pragma unroll
      for (int m = 0; m < 5; ++m) {
        const bf16x8 af = *(const bf16x8*)&Pfrag[(((ks * 5 + m) * 64) + slot) * 8];
        acc[m] = __builtin_amdgcn_mfma_f32_16x16x32_bf16(af, bu.v, acc[m], 0, 0, 0);
      }
    }
  }

  // D frag: col = lane&15 (channel), row = (lane>>4)*4 + q (class).
  __half* po = partial + ((size_t)(b * 256 + jp * 2 + half)) * (80 * 64);
  #pragma unroll
  for (int m = 0; m < 5; ++m) {
    #pragma unroll
    for (int q = 0; q < 4; ++q) {
      const int n = m * 16 + kg * 4 + q;
      po[n * 64 + c0 + ch16] = __float2half(acc[m][q]);
    }
  }
}

// ---------------- Kernel 1b: round-8 fallback (tiny ws) ----------------
__global__ __launch_bounds__(256) void k_assemble_full(
    const float* __restrict__ feat, const float* __restrict__ pred,
    __half* __restrict__ partial) {
  __shared__ __align__(16) unsigned short Pfrag[40 * 64 * 8];  // 40 KB

  const int tid = threadIdx.x;
  const int b  = blockIdx.x >> 7;
  const int rb = blockIdx.x & 127;
  const int wid = tid >> 6, l = tid & 63;
  const int ch16 = l & 15, kg = l >> 4;
  const int c0 = wid << 4;
  const int h0 = rb * 2;
  const int gg = tid & 31, nb = tid >> 5;

  f32x4 acc[5] = {};
  const float* fwave = feat + (((size_t)(b * 64 + c0 + ch16)) << 16);
  const float* pbat  = pred + (((size_t)(b * 80)) << 14);

  #pragma unroll
  for (int r = 0; r < 2; ++r) {
    const int h = h0 + r;
    const int j = h >> 1;
    int r0, r1; float wy0, wy1;
    if ((h & 1) == 0) { r0 = (j > 0) ? j - 1 : 0; r1 = j; wy0 = 0.25f; wy1 = 0.75f; }
    else              { r0 = j; r1 = (j < 127) ? j + 1 : 127; wy0 = 0.75f; wy1 = 0.25f; }

    float4 p0[10], p1[10];
    #pragma unroll
    for (int i = 0; i < 10; ++i) {
      const float* pb = pbat + (((size_t)(nb + 8 * i)) << 14);
      p0[i] = *(const float4*)(pb + (r0 << 7) + gg * 4);
      p1[i] = *(const float4*)(pb + (r1 << 7) + gg * 4);
    }
    SCHED_FENCE();

    const float* fb = fwave + h * 256;
    float4 f[16];
    #pragma unroll
    for (int ks = 0; ks < 8; ++ks) {
      const int pw = ks * 32 + kg * 8;
      f[2 * ks]     = *(const float4*)(fb + pw);
      f[2 * ks + 1] = *(const float4*)(fb + pw + 4);
    }
    SCHED_FENCE();

    #pragma unroll
    for (int i = 0; i < 10; ++i) {
      const int n = nb + 8 * i;
      const float y0 = wy0 * p0[i].x + wy1 * p1[i].x;
      const float y1 = wy0 * p0[i].y + wy1 * p1[i].y;
      const float y2 = wy0 * p0[i].z + wy1 * p1[i].z;
      const float y3 = wy0 * p0[i].w + wy1 * p1[i].w;
      float yl = __shfl_up(y3, 1, 64);   if (gg == 0)  yl = y0;
      float yr = __shfl_down(y0, 1, 64); if (gg == 31) yr = y3;
      float P[8];
      P[0] = sigAB(yl, y0); P[1] = sigBA(y0, y1);
      P[2] = sigAB(y0, y1); P[3] = sigBA(y1, y2);
      P[4] = sigAB(y1, y2); P[5] = sigBA(y2, y3);
      P[6] = sigAB(y2, y3); P[7] = sigBA(y3, yr);
      uint4 s;
      s.x = pk2(P[0], P[1]); s.y = pk2(P[2], P[3]);
      s.z = pk2(P[4], P[5]); s.w = pk2(P[6], P[7]);
      const int ks = gg >> 2, kgw = gg & 3;
      const int slot = kgw * 16 + (((n & 15) ^ ks ^ (kgw << 1)) & 15);
      *(uint4*)&Pfrag[(((ks * 5 + (n >> 4)) * 64) + slot) * 8] = s;
    }
    LGKM_BARRIER();

    #pragma unroll
    for (int ks = 0; ks < 8; ++ks) {
      const float4 f0 = f[2 * ks], f1 = f[2 * ks + 1];
      union { uint4 u; bf16x8 v; } bu;
      bu.u.x = pk2(f0.x, f0.y); bu.u.y = pk2(f0.z, f0.w);
      bu.u.z = pk2(f1.x, f1.y); bu.u.w = pk2(f1.z, f1.w);
      const int slot = kg * 16 + ((ch16 ^ ks ^ (kg << 1)) & 15);
      #pragma unroll
      for (int m = 0; m < 5; ++m) {
        const bf16x8 af = *(const bf16x8*)&Pfrag[(((ks * 5 + (m)) * 64) + slot) * 8];
        acc[m] = __builtin_amdgcn_mfma_f32_16x16x32_bf16(af, bu.v, acc[m], 0, 0, 0);
      }
    }
    LGKM_BARRIER();
  }

  __half* po = partial + ((size_t)(b * 128 + rb)) * (80 * 64);
  #pragma unroll
  for (int m = 0; m < 5; ++m) {
    #pragma unroll
    for (int q = 0; q < 4; ++q) {
      const int n = m * 16 + kg * 4 + q;
      po[n * 64 + c0 + ch16] = __float2half(acc[m][q]);
    }
  }
}

// ---------------- Kernel 2: reduce + head-update chain ----------------
__device__ __forceinline__ float wred64(float v) {
  #pragma unroll
  for (int off = 32; off > 0; off >>= 1) v += __shfl_xor(v, off, 64);
  return v;
}
__device__ __forceinline__ float lnorm(float x, const float* __restrict__ g,
                                       const float* __restrict__ be, int l) {
  const float m = wred64(x) * 0.015625f;
  const float d = x - m;
  const float var = wred64(d * d) * 0.015625f;
  return d * rsqrtf(var + 1e-5f) * g[l] + be[l];
}
__device__ __forceinline__ float sigmf(float x) {
  return __builtin_amdgcn_rcpf(1.0f + __builtin_amdgcn_exp2f(-1.44269504f * x));
}

// grid = 640 blocks (one per output row), 256 threads.
__global__ __launch_bounds__(256) void k_head(
    const __half* __restrict__ partial, const float* __restrict__ head,
    const float* __restrict__ Wpt, const float* __restrict__ bpt,
    const float* __restrict__ Wht, const float* __restrict__ bht,
    const float* __restrict__ Wpg, const float* __restrict__ bpg,
    const float* __restrict__ Whg, const float* __restrict__ bhg,
    const float* __restrict__ Wfc, const float* __restrict__ bfc,
    const float* __restrict__ g_pin, const float* __restrict__ be_pin,
    const float* __restrict__ g_hin, const float* __restrict__ be_hin,
    const float* __restrict__ g_pout, const float* __restrict__ be_pout,
    const float* __restrict__ g_hout, const float* __restrict__ be_hout,
    const float* __restrict__ g_fc, const float* __restrict__ be_fc,
    float* __restrict__ out, int npart) {
  __shared__ float red[4][64];
  __shared__ float buf[4][64];   // a, hd, gate, upd
  const int tid = threadIdx.x, c = tid & 63, q = tid >> 6;
  const int r = blockIdx.x;              // [0,640)
  const int b = r / 80, n = r % 80;
  const int npq = npart >> 2;

  const __half* pp = partial + ((size_t)b * npart + (size_t)q * npq) * 5120 + n * 64 + c;
  float s = 0.f;
  #pragma unroll 8
  for (int jj = 0; jj < npq; ++jj) s += __half2float(pp[(size_t)jj * 5120]);
  red[q][c] = s;
  __syncthreads();

  if (q == 0) {
    const float a_c = red[0][c] + red[1][c] + red[2][c] + red[3][c];
    buf[0][c] = a_c;
    buf[1][c] = head[(size_t)r * 64 + c];

    float pf_in = bpt[c], pf_out = bpt[64 + c];
    float hf_in = bht[c], hf_out = bht[64 + c];
    #pragma unroll 8
    for (int k = 0; k < 64; ++k) {
      const float av = buf[0][k];
      const float hv = buf[1][k];
      pf_in  += av * Wpt[k * 128 + c];
      pf_out += av * Wpt[k * 128 + 64 + c];
      hf_in  += hv * Wht[k * 128 + c];
      hf_out += hv * Wht[k * 128 + 64 + c];
    }
    buf[2][c] = hf_in * pf_in;

    float hg = bhg[c], pg = bpg[c];
    #pragma unroll 8
    for (int k = 0; k < 64; ++k) {
      const float gv = buf[2][k];
      hg += gv * Whg[k * 64 + c];
      pg += gv * Wpg[k * 64 + c];
    }
    const float head_gate = sigmf(lnorm(hg, g_hin, be_hin, c));
    const float pred_gate = sigmf(lnorm(pg, g_pin, be_pin, c));
    const float hfo = lnorm(hf_out, g_hout, be_hout, c);
    const float pfo = lnorm(pf_out, g_pout, be_pout, c);
    buf[3][c] = pred_gate * pfo + head_gate * hfo;

    float fc = bfc[c];
    #pragma unroll 8
    for (int k = 0; k < 64; ++k)
      fc += buf[3][k] * Wfc[k * 64 + c];
    float o = lnorm(fc, g_fc, be_fc, c);
    out[(size_t)r * 64 + c] = fmaxf(o, 0.f);
  }
}

extern "C" void kernel_launch(void* const* d_in, const int* in_sizes, int n_in,
                              void* d_out, int out_size, void* d_ws, size_t ws_size,
                              hipStream_t stream) {
  const float* feat   = (const float*)d_in[0];
  const float* head   = (const float*)d_in[1];
  const float* pred   = (const float*)d_in[2];
  const float* Wpt    = (const float*)d_in[3];
  const float* bpt    = (const float*)d_in[4];
  const float* Wht    = (const float*)d_in[5];
  const float* bht    = (const float*)d_in[6];
  const float* Wpg    = (const float*)d_in[7];
  const float* bpg    = (const float*)d_in[8];
  const float* Whg    = (const float*)d_in[9];
  const float* bhg    = (const float*)d_in[10];
  const float* Wfc    = (const float*)d_in[11];
  const float* bfc    = (const float*)d_in[12];
  const float* g_pin  = (const float*)d_in[13];
  const float* be_pin = (const float*)d_in[14];
  const float* g_hin  = (const float*)d_in[15];
  const float* be_hin = (const float*)d_in[16];
  const float* g_pout = (const float*)d_in[17];
  const float* be_pout= (const float*)d_in[18];
  const float* g_hout = (const float*)d_in[19];
  const float* be_hout= (const float*)d_in[20];
  const float* g_fc   = (const float*)d_in[21];
  const float* be_fc  = (const float*)d_in[22];
  float* out = (float*)d_out;
  __half* partial = (__half*)d_ws;

  const bool big = ws_size >= (size_t)8 * 256 * 5120 * 2;  // 20.97 MB (<< proven 42 MB)
  const int npart = big ? 256 : 128;

  if (big)
    hipLaunchKernelGGL(k_assemble_pair, dim3(2048), dim3(256), 0, stream,
                       feat, pred, partial);
  else
    hipLaunchKernelGGL(k_assemble_full, dim3(1024), dim3(256), 0, stream,
                       feat, pred, partial);

  hipLaunchKernelGGL(k_head, dim3(640), dim3(256), 0, stream,
                     partial, head, Wpt, bpt, Wht, bht, Wpg, bpg, Whg, bhg,
                     Wfc, bfc, g_pin, be_pin, g_hin, be_hin, g_pout, be_pout,
                     g_hout, be_hout, g_fc, be_fc, out, npart);
}